// Round 4
// baseline (580.354 us; speedup 1.0000x reference)
//
#include <hip/hip_runtime.h>
#include <math.h>

#define GN 256
#define VOLN (GN * GN * GN)
#define VOLBYTES (VOLN * sizeof(float))
#define RAD 16   // truncation radius of the exact circular-conv kernel

// ---------------------------------------------------------------------------
// Splat: each point scatters trilinear weights into 8 voxels (atomicAdd).
// Out-of-bounds corners are dropped (JAX default scatter semantics).
// ---------------------------------------------------------------------------
__global__ void splat_kernel(const float* __restrict__ means,
                             const float* __restrict__ weights,
                             float* __restrict__ vol, int n) {
    int tid = blockIdx.x * blockDim.x + threadIdx.x;
    if (tid >= n) return;
    float g0 = fmaf(means[3 * tid + 0], 128.f, 128.f);
    float g1 = fmaf(means[3 * tid + 1], 128.f, 128.f);
    float g2 = fmaf(means[3 * tid + 2], 128.f, 128.f);
    float w  = fmaxf(weights[tid], 0.f);   // relu
    float f0 = floorf(g0), f1 = floorf(g1), f2 = floorf(g2);
    int   b0 = (int)f0, b1 = (int)f1, b2 = (int)f2;
    float r0 = g0 - f0, r1 = g1 - f1, r2 = g2 - f2;
    float c0[2] = {1.f - r0, r0};
    float c1[2] = {1.f - r1, r1};
    float c2[2] = {1.f - r2, r2};
#pragma unroll
    for (int o0 = 0; o0 < 2; ++o0) {
        int i0 = b0 + o0;
        if ((unsigned)i0 >= GN) continue;
#pragma unroll
        for (int o1 = 0; o1 < 2; ++o1) {
            int i1 = b1 + o1;
            if ((unsigned)i1 >= GN) continue;
            float w01 = c0[o0] * c1[o1] * w;
#pragma unroll
            for (int o2 = 0; o2 < 2; ++o2) {
                int i2 = b2 + o2;
                if ((unsigned)i2 >= GN) continue;
                atomicAdd(&vol[(i0 << 16) + (i1 << 8) + i2], w01 * c2[o2]);
            }
        }
    }
}

// ---------------------------------------------------------------------------
// Exact 1-D blur taps: h[m] = (1/256) * sum_k exp(-2*pi^2*sigma^2*f_k^2)
//                                       * cos(2*pi*k*m/256),  f_k = fftfreq
// (the FFT blur is exactly the separable circular convolution with h).
// ---------------------------------------------------------------------------
__global__ void taps_kernel(const float* __restrict__ sigma_param,
                            float* __restrict__ h) {
    int m = threadIdx.x;
    if (m > RAD) return;
    float s = fmaxf(sigma_param[0], 0.f);  // relu
    double c = 2.0 * M_PI * M_PI * (double)s * (double)s;
    double acc = 0.0;
    for (int k = 0; k < GN; ++k) {
        int kk = (k < GN / 2) ? k : k - GN;
        double f = (double)kk / (double)GN;
        acc += exp(-c * f * f) * cos(2.0 * M_PI * (double)k * (double)m / (double)GN);
    }
    h[m] = (float)(acc / (double)GN);
}

// ---------------------------------------------------------------------------
// Separable circular convolutions. Index: vol[i0][i1][i2], i2 contiguous.
// ---------------------------------------------------------------------------
__global__ void conv_d0(const float* __restrict__ in, float* __restrict__ out,
                        const float* __restrict__ h) {
    __shared__ float sh[RAD + 1];
    if (threadIdx.x <= RAD) sh[threadIdx.x] = h[threadIdx.x];
    __syncthreads();
    int i2 = threadIdx.x;
    int i1 = blockIdx.x;
    int i0 = blockIdx.y;
    float acc = sh[0] * in[(i0 << 16) + (i1 << 8) + i2];
#pragma unroll
    for (int d = 1; d <= RAD; ++d) {
        int p = (i0 + d) & (GN - 1);
        int q = (i0 - d) & (GN - 1);
        acc += sh[d] * (in[(p << 16) + (i1 << 8) + i2] +
                        in[(q << 16) + (i1 << 8) + i2]);
    }
    out[(i0 << 16) + (i1 << 8) + i2] = acc;
}

__global__ void conv_d1(const float* __restrict__ in, float* __restrict__ out,
                        const float* __restrict__ h) {
    __shared__ float sh[RAD + 1];
    if (threadIdx.x <= RAD) sh[threadIdx.x] = h[threadIdx.x];
    __syncthreads();
    int i2 = threadIdx.x;
    int i1 = blockIdx.x;
    int i0 = blockIdx.y;
    float acc = sh[0] * in[(i0 << 16) + (i1 << 8) + i2];
#pragma unroll
    for (int d = 1; d <= RAD; ++d) {
        int p = (i1 + d) & (GN - 1);
        int q = (i1 - d) & (GN - 1);
        acc += sh[d] * (in[(i0 << 16) + (p << 8) + i2] +
                        in[(i0 << 16) + (q << 8) + i2]);
    }
    out[(i0 << 16) + (i1 << 8) + i2] = acc;
}

__global__ void conv_d2(const float* __restrict__ in, float* __restrict__ out,
                        const float* __restrict__ h) {
    __shared__ float line[GN];
    __shared__ float sh[RAD + 1];
    int x = threadIdx.x;
    if (x <= RAD) sh[x] = h[x];
    int i1 = blockIdx.x;
    int i0 = blockIdx.y;
    line[x] = in[(i0 << 16) + (i1 << 8) + x];
    __syncthreads();
    float acc = sh[0] * line[x];
#pragma unroll
    for (int d = 1; d <= RAD; ++d) {
        acc += sh[d] * (line[(x + d) & (GN - 1)] + line[(x - d) & (GN - 1)]);
    }
    out[(i0 << 16) + (i1 << 8) + x] = acc;
}

// ---------------------------------------------------------------------------
extern "C" void kernel_launch(void* const* d_in, const int* in_sizes, int n_in,
                              void* d_out, int out_size, void* d_ws, size_t ws_size,
                              hipStream_t stream) {
    const float* means   = (const float*)d_in[0];
    const float* weights = (const float*)d_in[1];
    const float* sigma   = (const float*)d_in[2];
    int n = in_sizes[1];                       // 500000 points

    float* volA = (float*)d_ws;                // 64 MB scratch volume
    float* h    = (float*)((char*)d_ws + VOLBYTES);
    float* out  = (float*)d_out;

    hipMemsetAsync(volA, 0, VOLBYTES, stream);
    taps_kernel<<<1, 64, 0, stream>>>(sigma, h);
    splat_kernel<<<(n + 255) / 256, 256, 0, stream>>>(means, weights, volA, n);

    conv_d0<<<dim3(GN, GN), GN, 0, stream>>>(volA, out, h);   // blur dim0
    conv_d1<<<dim3(GN, GN), GN, 0, stream>>>(out, volA, h);   // blur dim1
    conv_d2<<<dim3(GN, GN), GN, 0, stream>>>(volA, out, h);   // blur dim2
}